// Round 13
// baseline (187.382 us; speedup 1.0000x reference)
//
#include <hip/hip_runtime.h>
#include <hip/hip_bf16.h>
#include <stdint.h>

// B=8, N=1024, D=768, H=12, hd=64
// cvt(x,Wqkv,Wproj -> bf16 ws) -> pipelined MFMA gemm qkv -> MFMA flash attention -> pipelined MFMA gemm proj

typedef unsigned short u16;
typedef unsigned int u32;
typedef __attribute__((ext_vector_type(8))) short short8;
typedef __attribute__((ext_vector_type(4))) float f32x4;

#define MFMA16(a, b, c) __builtin_amdgcn_mfma_f32_16x16x32_bf16((a), (b), (c), 0, 0, 0)

static __device__ __forceinline__ u16 f2bf(float f) {
    __hip_bfloat16 h = __float2bfloat16(f);
    return *(u16*)&h;
}
// async global->LDS, 16B per lane; LDS dest must be wave-uniform base + lane*16
static __device__ __forceinline__ void gld16(const u16* g, u16* l) {
  __builtin_amdgcn_global_load_lds(
      (const __attribute__((address_space(1))) void*)g,
      (__attribute__((address_space(3))) void*)l, 16, 0, 0);
}

// ---------------- fp32 -> bf16 conversion of the three input tensors
__global__ __launch_bounds__(256) void cvt_bf16(
    const float* __restrict__ s0, u16* __restrict__ d0, int n0,
    const float* __restrict__ s1, u16* __restrict__ d1, int n1,
    const float* __restrict__ s2, u16* __restrict__ d2, int n2) {
  int i = (blockIdx.x * 256 + threadIdx.x) * 4;
  const float* s; u16* d;
  if (i < n0) { s = s0 + i; d = d0 + i; }
  else if ((i -= n0) < n1) { s = s1 + i; d = d1 + i; }
  else if ((i -= n1) < n2) { s = s2 + i; d = d2 + i; }
  else return;
  float4 v = *(const float4*)s;
  ushort4 o;
  o.x = f2bf(v.x); o.y = f2bf(v.y); o.z = f2bf(v.z); o.w = f2bf(v.w);
  *(ushort4*)d = o;
}

// ---------------- QKV GEMM, pipelined, BK=32, flat phase (r12, verified).
// BM=256 BN=128, 512 thr, LDS 48KB -> 2 blocks/CU. Flat phase: all 10 b128
// frags up-front (forces fat VGPR schedule vs r11's 56-reg serialization),
// lgkm(0)+sched_barrier+barrier, restage(t+2), 16 MFMA setprio, vmcnt(3).
// Swizzle ch ^= (row>>1)&3 both-sides. T1 chunked XCD swizzle.
__global__ __launch_bounds__(512, 4) void gemm_qkv_p32(
    const u16* __restrict__ A,
    const u16* __restrict__ B,
    u16* __restrict__ C) {
  constexpr int K = 768, LDC = 2304, NTIL = K / 32;   // 24 K-tiles
  __shared__ u16 lds[2][(256 + 128) * 32];            // 48 KB
  const int tid = threadIdx.x;
  const int w = tid >> 6, l = tid & 63;
  const int lane16 = l & 15, quad = l >> 4;
  const int wr = w >> 2, wc = w & 3;

  const int orig = blockIdx.x;
  const int logical = (orig & 7) * 72 + (orig >> 3);  // bijective, 576/8=72
  const int i0 = (logical / 18) * 256, j0 = (logical % 18) * 128;

  f32x4 acc[8][2];
  #pragma unroll
  for (int m = 0; m < 8; m++)
    #pragma unroll
    for (int n = 0; n < 2; n++) acc[m][n] = (f32x4){0.f, 0.f, 0.f, 0.f};

  auto stage = [&](int buf, int t) {
    const int k0 = t * 32;
    u16* Ad = &lds[buf][0];
    #pragma unroll
    for (int s = 0; s < 2; s++) {
      int lin = tid + s * 512;
      int row = lin >> 2, j = lin & 3;
      gld16(&A[(size_t)(i0 + row) * K + k0 + ((j ^ ((row >> 1) & 3)) * 8)], &Ad[lin * 8]);
    }
    {
      u16* Bd = &lds[buf][256 * 32];
      int row = tid >> 2, j = tid & 3;
      gld16(&B[(size_t)(j0 + row) * K + k0 + ((j ^ ((row >> 1) & 3)) * 8)], &Bd[tid * 8]);
    }
  };

  stage(0, 0);
  stage(1, 1);                                        // 6 loads in flight
  asm volatile("s_waitcnt vmcnt(3)" ::: "memory");    // tile 0 landed
  __builtin_amdgcn_s_barrier();

  for (int t = 0; t < NTIL; t++) {
    const u16* Al = &lds[t & 1][0];
    const u16* Bl = &lds[t & 1][256 * 32];
    short8 bf[2], af[8];
    #pragma unroll
    for (int n = 0; n < 2; n++) {
      int row = wc * 32 + n * 16 + lane16;
      int ch = quad ^ ((row >> 1) & 3);
      bf[n] = *(const short8*)&Bl[row * 32 + ch * 8];
    }
    #pragma unroll
    for (int mi = 0; mi < 8; mi++) {
      int row = wr * 128 + mi * 16 + lane16;
      int ch = quad ^ ((row >> 1) & 3);
      af[mi] = *(const short8*)&Al[row * 32 + ch * 8];
    }
    asm volatile("s_waitcnt lgkmcnt(0)" ::: "memory");
    __builtin_amdgcn_sched_barrier(0);
    __builtin_amdgcn_s_barrier();
    if (t + 2 < NTIL) stage(t & 1, t + 2);
    __builtin_amdgcn_s_setprio(1);
    #pragma unroll
    for (int mi = 0; mi < 8; mi++)
      #pragma unroll
      for (int n = 0; n < 2; n++)
        acc[mi][n] = MFMA16(af[mi], bf[n], acc[mi][n]);
    __builtin_amdgcn_s_setprio(0);
    if (t + 2 < NTIL) asm volatile("s_waitcnt vmcnt(3)" ::: "memory");
    else              asm volatile("s_waitcnt vmcnt(0)" ::: "memory");
    __builtin_amdgcn_s_barrier();
  }

  #pragma unroll
  for (int m = 0; m < 8; m++) {
    #pragma unroll
    for (int n = 0; n < 2; n++) {
      int col = j0 + wc * 32 + n * 16 + lane16;
      #pragma unroll
      for (int r = 0; r < 4; r++) {
        int row = i0 + wr * 128 + m * 16 + quad * 4 + r;
        C[(size_t)row * LDC + col] = f2bf(acc[m][n][r]);
      }
    }
  }
}

// ---------------- proj GEMM, pipelined, BK=32 (r11, verified: not in top-5).
__global__ __launch_bounds__(256, 3) void gemm_proj_p32(
    const u16* __restrict__ A,
    const u16* __restrict__ B,
    float* __restrict__ C,
    const float* __restrict__ bias) {
  constexpr int K = 768, LDC = 768, NTIL = K / 32;    // 24 K-tiles
  __shared__ u16 lds[2][(128 + 64) * 32];             // 24 KB
  const int tid = threadIdx.x;
  const int w = tid >> 6, l = tid & 63;
  const int lane16 = l & 15, quad = l >> 4;
  const int mh = (w & 1) * 64;
  const int nh = (w >> 1) * 32;

  const int orig = blockIdx.x;
  const int logical = (orig & 7) * 96 + (orig >> 3);  // bijective, 768/8=96
  const int i0 = (logical / 12) * 128, j0 = (logical % 12) * 64;

  f32x4 acc[4][2];
  #pragma unroll
  for (int m = 0; m < 4; m++)
    #pragma unroll
    for (int n = 0; n < 2; n++) acc[m][n] = (f32x4){0.f, 0.f, 0.f, 0.f};

  auto stage = [&](int buf, int t) {
    const int k0 = t * 32;
    u16* Ad = &lds[buf][0];
    #pragma unroll
    for (int s = 0; s < 2; s++) {
      int lin = tid + s * 256;
      int row = lin >> 2, j = lin & 3;
      gld16(&A[(size_t)(i0 + row) * K + k0 + ((j ^ ((row >> 1) & 3)) * 8)], &Ad[lin * 8]);
    }
    {
      u16* Bd = &lds[buf][128 * 32];
      int row = tid >> 2, j = tid & 3;
      gld16(&B[(size_t)(j0 + row) * K + k0 + ((j ^ ((row >> 1) & 3)) * 8)], &Bd[tid * 8]);
    }
  };

  stage(0, 0);
  stage(1, 1);                                        // 6 loads in flight
  asm volatile("s_waitcnt vmcnt(3)" ::: "memory");    // tile 0 landed
  __builtin_amdgcn_s_barrier();

  for (int t = 0; t < NTIL; t++) {
    const u16* Al = &lds[t & 1][0];
    const u16* Bl = &lds[t & 1][128 * 32];
    short8 bf[2];
    #pragma unroll
    for (int n = 0; n < 2; n++) {
      int row = nh + n * 16 + lane16;
      int ch = quad ^ ((row >> 1) & 3);
      bf[n] = *(const short8*)&Bl[row * 32 + ch * 8];
    }
    #pragma unroll
    for (int p = 0; p < 2; p++) {
      short8 af[2];
      #pragma unroll
      for (int mi = 0; mi < 2; mi++) {
        int row = mh + (2 * p + mi) * 16 + lane16;
        int ch = quad ^ ((row >> 1) & 3);
        af[mi] = *(const short8*)&Al[row * 32 + ch * 8];
      }
      if (p == 1) {
        asm volatile("s_waitcnt lgkmcnt(0)" ::: "memory");
        __builtin_amdgcn_sched_barrier(0);
        __builtin_amdgcn_s_barrier();
        if (t + 2 < NTIL) stage(t & 1, t + 2);
      }
      __builtin_amdgcn_s_setprio(1);
      #pragma unroll
      for (int mi = 0; mi < 2; mi++)
        #pragma unroll
        for (int n = 0; n < 2; n++)
          acc[2 * p + mi][n] = MFMA16(af[mi], bf[n], acc[2 * p + mi][n]);
      __builtin_amdgcn_s_setprio(0);
    }
    if (t + 2 < NTIL) asm volatile("s_waitcnt vmcnt(3)" ::: "memory");
    else              asm volatile("s_waitcnt vmcnt(0)" ::: "memory");
    __builtin_amdgcn_s_barrier();
  }

  #pragma unroll
  for (int m = 0; m < 4; m++) {
    #pragma unroll
    for (int n = 0; n < 2; n++) {
      int col = j0 + nh + n * 16 + lane16;
      #pragma unroll
      for (int r = 0; r < 4; r++) {
        int row = i0 + mh + m * 16 + quad * 4 + r;
        C[(size_t)row * LDC + col] = acc[m][n][r] + bias[col];
      }
    }
  }
}

// ---------------- Attention: MFMA flash, transposed-S, fixed-max softmax.
// r13: K/V LDS DOUBLE-BUFFER -> ONE barrier per chunk (was 2). Write chunk c
// into buf c&1 (safe: any wave past barrier(c-1) finished compute(c-2), the
// last reader of this buffer, by program order), then a single publish
// barrier, then compute from buf. To fit dbuf in the 3-blocks/CU LDS budget
// (<=54.6KB), tiles drop from pad-72 to 64-wide rows with the PMC-verified
// XOR chunk-swizzle (16B chunk ^= row&7; write and read apply the same
// involution): LDS = 2*16K(Ks)+2*16K(Vt)+16K(Ps)+4K(mkb) = 53.2KB.
// Carries r2 T14 async-STAGE + setprio, r3 mkb_all, r8 K0-fold + cvt_pk.
// Block = 4 waves, 128 q-rows, grid 768 (3 blocks/CU).
__global__ __launch_bounds__(256, 3) void attn_mfma(
    const u16* __restrict__ qkv,   // bf16 bits, [B*N][2304]; q +0, k +768, v +1536 (+h*64)
    const int* __restrict__ mask,
    u16* __restrict__ ctx) {
  __shared__ u16 Ks[2][64][64];   // [buf][key][dim]  (XOR-swizzled chunks)
  __shared__ u16 Vt[2][64][64];   // [buf][dim][key]  (XOR-swizzled chunks)
  __shared__ u16 Ps[4][32][64];   // per-wave P [qrow][key] (XOR-swizzled)
  __shared__ float mkb_all[1024]; // K0 (valid) or -1e38 (masked) per key

  const int tid = threadIdx.x;
  const int w = tid >> 6, l = tid & 63;
  const int lane16 = l & 15, quad = l >> 4;
  const int idx = blockIdx.x;
  const int bh = idx % 96;        // 96 % 8 == 0 -> same bh => same XCD
  const int rb = idx / 96;
  const int b = bh / 12, h = bh % 12;
  const int n0 = rb * 128;
  const int baseRow = b * 1024;

  // exp(s/8 - 16) == exp2(s*K1 + K0); fixed max >> max score (~8 sigma), overflow-free.
  const float K1 = 0.18033688011112043f;   // log2(e)/8
  const float K0 = -23.083120654223415f;   // -16*log2(e)

  // staging thread mapping
  const int key_s = tid >> 2, ds_s = (tid & 3) * 16;      // K: 1 key, 32 dims
  const int kA_s = (tid & 31) * 2, dg_s = tid >> 5;       // V: 2 keys, 8 dims

  // whole-sequence mask bias table (written once; first publish barrier covers it)
  {
    int4 mv = *(const int4*)&mask[baseRow + tid * 4];
    f32x4 mf;
    mf[0] = mv.x ? K0 : -1e38f;
    mf[1] = mv.y ? K0 : -1e38f;
    mf[2] = mv.z ? K0 : -1e38f;
    mf[3] = mv.w ? K0 : -1e38f;
    *(f32x4*)&mkb_all[tid * 4] = mf;
  }

  // Q fragments (used as MFMA B operand): n=lane16 (local qrow), k=quad*8+j
  short8 qfrag[2][2];
  #pragma unroll
  for (int qt = 0; qt < 2; qt++) {
    const u16* qp = qkv + (size_t)(baseRow + n0 + w*32 + qt*16 + lane16) * 2304 + h*64;
    #pragma unroll
    for (int ks = 0; ks < 2; ks++)
      qfrag[qt][ks] = *(const short8*)(qp + ks*32 + quad*8);
  }

  f32x4 oacc[2][4];     // [qt][nt(dim)]; C-layout row=quad*4+r=qrow, col=lane16=dim
  #pragma unroll
  for (int qt = 0; qt < 2; qt++)
    #pragma unroll
    for (int nt = 0; nt < 4; nt++) oacc[qt][nt] = (f32x4){0.f, 0.f, 0.f, 0.f};
  f32x4 lsum4[2] = {(f32x4){0.f,0.f,0.f,0.f}, (f32x4){0.f,0.f,0.f,0.f}};

  // ---- T14 prologue: issue chunk-0 K/V loads into registers
  uint4 kr0, kr1, vr0, vr1;
  {
    const u16* kp = qkv + (size_t)(baseRow + key_s) * 2304 + 768 + h*64 + ds_s;
    kr0 = *(const uint4*)kp;
    kr1 = *(const uint4*)(kp + 8);
    const u16* vp = qkv + (size_t)(baseRow + kA_s) * 2304 + 1536 + h*64 + dg_s*8;
    vr0 = *(const uint4*)vp;
    vr1 = *(const uint4*)(vp + 2304);
  }

  for (int c = 0; c < 16; c++) {
    const int buf = c & 1;
    // ---- write staged registers (chunk c) into LDS buf (swizzled chunks)
    {
      int ch0 = ds_s >> 3;                 // logical 16B-chunk: ds_s/8
      int sw = key_s & 7;
      *(uint4*)&Ks[buf][key_s][((ch0 ^ sw) << 3)]       = kr0;
      *(uint4*)&Ks[buf][key_s][(((ch0 + 1) ^ sw) << 3)] = kr1;
    }
    {
      const u16* va = (const u16*)&vr0;
      const u16* vb = (const u16*)&vr1;
      int chv = (tid & 31) >> 2;           // logical chunk of key-pair kA_s
      int off = kA_s & 7;                  // u16 offset within chunk
      #pragma unroll
      for (int j = 0; j < 8; j++) {
        int row = dg_s * 8 + j;
        *(u32*)&Vt[buf][row][((chv ^ (row & 7)) << 3) + off] =
            (u32)va[j] | ((u32)vb[j] << 16);
      }
    }
    // ---- issue chunk c+1's global loads (latency hides under compute of c)
    if (c + 1 < 16) {
      const u16* kp = qkv + (size_t)(baseRow + (c+1)*64 + key_s) * 2304 + 768 + h*64 + ds_s;
      kr0 = *(const uint4*)kp;
      kr1 = *(const uint4*)(kp + 8);
      const u16* vp = qkv + (size_t)(baseRow + (c+1)*64 + kA_s) * 2304 + 1536 + h*64 + dg_s*8;
      vr0 = *(const uint4*)vp;
      vr1 = *(const uint4*)(vp + 2304);
    }
    __syncthreads();          // single publish barrier per chunk

    // S^T = K * Q^T : A=K (m=key), B=Q (n=qrow). C-layout: row=key, col=qrow.
    f32x4 sacc[4][2];
    #pragma unroll
    for (int kt = 0; kt < 4; kt++)
      #pragma unroll
      for (int qt = 0; qt < 2; qt++) sacc[kt][qt] = (f32x4){0.f, 0.f, 0.f, 0.f};
    #pragma unroll
    for (int ks = 0; ks < 2; ks++) {
      short8 kf[4];
      #pragma unroll
      for (int kt = 0; kt < 4; kt++) {
        int row = kt*16 + lane16;
        int ch = (4*ks + quad) ^ (row & 7);
        kf[kt] = *(const short8*)&Ks[buf][row][ch << 3];
      }
      __builtin_amdgcn_s_setprio(1);
      #pragma unroll
      for (int kt = 0; kt < 4; kt++)
        #pragma unroll
        for (int qt = 0; qt < 2; qt++)
          sacc[kt][qt] = MFMA16(kf[kt], qfrag[qt][ks], sacc[kt][qt]);
      __builtin_amdgcn_s_setprio(0);
    }

    // softmax: e = exp2(fma(s, K1, mkb)) — mask bias IS the exp2 offset.
    // P-pack via v_cvt_pk_bf16_f32; P write at swizzled chunk.
    #pragma unroll
    for (int kt = 0; kt < 4; kt++) {
      f32x4 mk4 = *(const f32x4*)&mkb_all[c*64 + kt*16 + quad*4];   // contiguous keys
      #pragma unroll
      for (int qt = 0; qt < 2; qt++) {
        float e0 = __builtin_amdgcn_exp2f(fmaf(sacc[kt][qt][0], K1, mk4[0]));
        float e1 = __builtin_amdgcn_exp2f(fmaf(sacc[kt][qt][1], K1, mk4[1]));
        float e2 = __builtin_amdgcn_exp2f(fmaf(sacc[kt][qt][2], K1, mk4[2]));
        float e3 = __builtin_amdgcn_exp2f(fmaf(sacc[kt][qt][3], K1, mk4[3]));
        lsum4[qt][0] += e0; lsum4[qt][1] += e1;
        lsum4[qt][2] += e2; lsum4[qt][3] += e3;
        uint2 pv;
        asm("v_cvt_pk_bf16_f32 %0, %1, %2" : "=v"(pv.x) : "v"(e0), "v"(e1));
        asm("v_cvt_pk_bf16_f32 %0, %1, %2" : "=v"(pv.y) : "v"(e2), "v"(e3));
        int prow = qt*16 + lane16;
        int pch = (2*kt + (quad >> 1)) ^ (prow & 7);   // logical chunk of col kt*16+quad*4
        *(uint2*)&Ps[w][prow][(pch << 3) + (quad & 1) * 4] = pv;
      }
    }

    // O += P * V : A=P (m=qrow, k=key) own-wave LDS; B=V^T (n=dim, k=key) from Vt.
    #pragma unroll
    for (int kc = 0; kc < 2; kc++) {
      short8 pf[2], vf[4];
      #pragma unroll
      for (int qt = 0; qt < 2; qt++) {
        int row = qt*16 + lane16;
        int ch = (4*kc + quad) ^ (row & 7);
        pf[qt] = *(const short8*)&Ps[w][row][ch << 3];
      }
      #pragma unroll
      for (int nt = 0; nt < 4; nt++) {
        int row = nt*16 + lane16;
        int ch = (4*kc + quad) ^ (row & 7);
        vf[nt] = *(const short8*)&Vt[buf][row][ch << 3];
      }
      __builtin_amdgcn_s_setprio(1);
      #pragma unroll
      for (int qt = 0; qt < 2; qt++)
        #pragma unroll
        for (int nt = 0; nt < 4; nt++)
          oacc[qt][nt] = MFMA16(pf[qt], vf[nt], oacc[qt][nt]);
      __builtin_amdgcn_s_setprio(0);
    }
  }

  // lsum: reduce across quads, then redistribute to the C-layout row owner.
  float linv[2][4];
  #pragma unroll
  for (int qt = 0; qt < 2; qt++) {
    float s = lsum4[qt][0] + lsum4[qt][1] + lsum4[qt][2] + lsum4[qt][3];
    s += __shfl_xor(s, 16);
    s += __shfl_xor(s, 32);   // every lane: total for qrow = its lane16 (tile qt)
    #pragma unroll
    for (int r = 0; r < 4; r++)
      linv[qt][r] = 1.0f / __shfl(s, quad*4 + r);
  }
  // store; masked query rows get exactly their own V row (bit-exact copy)
  #pragma unroll
  for (int qt = 0; qt < 2; qt++) {
    #pragma unroll
    for (int r = 0; r < 4; r++) {
      int rl = w*32 + qt*16 + quad*4 + r;
      int rg = n0 + rl;
      int mq = (mkb_all[n0 + rl] != -1e38f);
      #pragma unroll
      for (int nt = 0; nt < 4; nt++) {
        u16 outv;
        if (mq) {
          outv = f2bf(oacc[qt][nt][r] * linv[qt][r]);
        } else {
          outv = qkv[(size_t)(baseRow + rg) * 2304 + 1536 + h*64 + nt*16 + lane16];
        }
        ctx[(size_t)(baseRow + rg) * 768 + h*64 + nt*16 + lane16] = outv;
      }
    }
  }
}

extern "C" void kernel_launch(void* const* d_in, const int* in_sizes, int n_in,
                              void* d_out, int out_size, void* d_ws, size_t ws_size,
                              hipStream_t stream) {
  const float* x     = (const float*)d_in[0];
  const int*   mask  = (const int*)d_in[1];
  const float* Wqkv  = (const float*)d_in[2];
  const float* Wproj = (const float*)d_in[3];
  const float* bproj = (const float*)d_in[4];
  float* out = (float*)d_out;

  const int NX = 8192 * 768;
  const int NQ = 2304 * 768;
  const int NP = 768 * 768;

  char* wsb = (char*)d_ws;
  u16* qkv    = (u16*)wsb;                                  // 37.75 MB
  u16* ctx    = (u16*)(wsb + (size_t)8192 * 2304 * 2);      // 12.58 MB
  u16* xb     = (u16*)(wsb + (size_t)8192 * 2304 * 2 + (size_t)8192 * 768 * 2);
  u16* wqkvb  = xb + NX;
  u16* wprojb = wqkvb + NQ;

  int cvt_blocks = ((NX + NQ + NP) / 4 + 255) / 256;
  cvt_bf16<<<dim3(cvt_blocks), 256, 0, stream>>>(x, xb, NX, Wqkv, wqkvb, NQ, Wproj, wprojb, NP);

  gemm_qkv_p32<<<dim3(576), 512, 0, stream>>>(xb, wqkvb, qkv);
  attn_mfma<<<dim3(768), 256, 0, stream>>>(qkv, mask, ctx);
  gemm_proj_p32<<<dim3(768), 256, 0, stream>>>(ctx, wprojb, out, bproj);
}

// Round 14
// 182.774 us; speedup vs baseline: 1.0252x; 1.0252x over previous
//
#include <hip/hip_runtime.h>
#include <hip/hip_bf16.h>
#include <stdint.h>

// B=8, N=1024, D=768, H=12, hd=64
// cvt(x,Wqkv,Wproj -> bf16 ws) -> pipelined MFMA gemm qkv -> MFMA flash attention -> pipelined MFMA gemm proj
// r14: attn reverted to r12 exact text (r13 single-barrier+swizzle regressed:
// VALU addressing cost > barrier savings); proj gets the r12 flat-phase fix.

typedef unsigned short u16;
typedef unsigned int u32;
typedef __attribute__((ext_vector_type(8))) short short8;
typedef __attribute__((ext_vector_type(4))) float f32x4;

#define MFMA16(a, b, c) __builtin_amdgcn_mfma_f32_16x16x32_bf16((a), (b), (c), 0, 0, 0)

static __device__ __forceinline__ u16 f2bf(float f) {
    __hip_bfloat16 h = __float2bfloat16(f);
    return *(u16*)&h;
}
// async global->LDS, 16B per lane; LDS dest must be wave-uniform base + lane*16
static __device__ __forceinline__ void gld16(const u16* g, u16* l) {
  __builtin_amdgcn_global_load_lds(
      (const __attribute__((address_space(1))) void*)g,
      (__attribute__((address_space(3))) void*)l, 16, 0, 0);
}

// ---------------- fp32 -> bf16 conversion of the three input tensors
__global__ __launch_bounds__(256) void cvt_bf16(
    const float* __restrict__ s0, u16* __restrict__ d0, int n0,
    const float* __restrict__ s1, u16* __restrict__ d1, int n1,
    const float* __restrict__ s2, u16* __restrict__ d2, int n2) {
  int i = (blockIdx.x * 256 + threadIdx.x) * 4;
  const float* s; u16* d;
  if (i < n0) { s = s0 + i; d = d0 + i; }
  else if ((i -= n0) < n1) { s = s1 + i; d = d1 + i; }
  else if ((i -= n1) < n2) { s = s2 + i; d = d2 + i; }
  else return;
  float4 v = *(const float4*)s;
  ushort4 o;
  o.x = f2bf(v.x); o.y = f2bf(v.y); o.z = f2bf(v.z); o.w = f2bf(v.w);
  *(ushort4*)d = o;
}

// ---------------- QKV GEMM, pipelined, BK=32, flat phase (r12, verified).
// BM=256 BN=128, 512 thr, LDS 48KB -> 2 blocks/CU. Flat phase: all 10 b128
// frags up-front (forces fat VGPR schedule vs r11's 56-reg serialization),
// lgkm(0)+sched_barrier+barrier, restage(t+2), 16 MFMA setprio, vmcnt(3).
// Swizzle ch ^= (row>>1)&3 both-sides. T1 chunked XCD swizzle.
__global__ __launch_bounds__(512, 4) void gemm_qkv_p32(
    const u16* __restrict__ A,
    const u16* __restrict__ B,
    u16* __restrict__ C) {
  constexpr int K = 768, LDC = 2304, NTIL = K / 32;   // 24 K-tiles
  __shared__ u16 lds[2][(256 + 128) * 32];            // 48 KB
  const int tid = threadIdx.x;
  const int w = tid >> 6, l = tid & 63;
  const int lane16 = l & 15, quad = l >> 4;
  const int wr = w >> 2, wc = w & 3;

  const int orig = blockIdx.x;
  const int logical = (orig & 7) * 72 + (orig >> 3);  // bijective, 576/8=72
  const int i0 = (logical / 18) * 256, j0 = (logical % 18) * 128;

  f32x4 acc[8][2];
  #pragma unroll
  for (int m = 0; m < 8; m++)
    #pragma unroll
    for (int n = 0; n < 2; n++) acc[m][n] = (f32x4){0.f, 0.f, 0.f, 0.f};

  auto stage = [&](int buf, int t) {
    const int k0 = t * 32;
    u16* Ad = &lds[buf][0];
    #pragma unroll
    for (int s = 0; s < 2; s++) {
      int lin = tid + s * 512;
      int row = lin >> 2, j = lin & 3;
      gld16(&A[(size_t)(i0 + row) * K + k0 + ((j ^ ((row >> 1) & 3)) * 8)], &Ad[lin * 8]);
    }
    {
      u16* Bd = &lds[buf][256 * 32];
      int row = tid >> 2, j = tid & 3;
      gld16(&B[(size_t)(j0 + row) * K + k0 + ((j ^ ((row >> 1) & 3)) * 8)], &Bd[tid * 8]);
    }
  };

  stage(0, 0);
  stage(1, 1);                                        // 6 loads in flight
  asm volatile("s_waitcnt vmcnt(3)" ::: "memory");    // tile 0 landed
  __builtin_amdgcn_s_barrier();

  for (int t = 0; t < NTIL; t++) {
    const u16* Al = &lds[t & 1][0];
    const u16* Bl = &lds[t & 1][256 * 32];
    short8 bf[2], af[8];
    #pragma unroll
    for (int n = 0; n < 2; n++) {
      int row = wc * 32 + n * 16 + lane16;
      int ch = quad ^ ((row >> 1) & 3);
      bf[n] = *(const short8*)&Bl[row * 32 + ch * 8];
    }
    #pragma unroll
    for (int mi = 0; mi < 8; mi++) {
      int row = wr * 128 + mi * 16 + lane16;
      int ch = quad ^ ((row >> 1) & 3);
      af[mi] = *(const short8*)&Al[row * 32 + ch * 8];
    }
    asm volatile("s_waitcnt lgkmcnt(0)" ::: "memory");
    __builtin_amdgcn_sched_barrier(0);
    __builtin_amdgcn_s_barrier();
    if (t + 2 < NTIL) stage(t & 1, t + 2);
    __builtin_amdgcn_s_setprio(1);
    #pragma unroll
    for (int mi = 0; mi < 8; mi++)
      #pragma unroll
      for (int n = 0; n < 2; n++)
        acc[mi][n] = MFMA16(af[mi], bf[n], acc[mi][n]);
    __builtin_amdgcn_s_setprio(0);
    if (t + 2 < NTIL) asm volatile("s_waitcnt vmcnt(3)" ::: "memory");
    else              asm volatile("s_waitcnt vmcnt(0)" ::: "memory");
    __builtin_amdgcn_s_barrier();
  }

  #pragma unroll
  for (int m = 0; m < 8; m++) {
    #pragma unroll
    for (int n = 0; n < 2; n++) {
      int col = j0 + wc * 32 + n * 16 + lane16;
      #pragma unroll
      for (int r = 0; r < 4; r++) {
        int row = i0 + wr * 128 + m * 16 + quad * 4 + r;
        C[(size_t)row * LDC + col] = f2bf(acc[m][n][r]);
      }
    }
  }
}

// ---------------- proj GEMM, pipelined, BK=32, flat phase (round 14).
// Same transformation that fixed qkv in r12 (r11 showed the allocator
// squeezes sibling kernels to serialized min-VGPR schedules): load all 6
// b128 frags up-front, lgkm(0)+sched_barrier+barrier, restage(t+2),
// 8 MFMA setprio, vmcnt(3) (never 0 in steady state).
// BM=128 BN=64, 256 thr, LDS 24KB, grid 768 = 3 blocks/CU.
__global__ __launch_bounds__(256, 3) void gemm_proj_p32(
    const u16* __restrict__ A,
    const u16* __restrict__ B,
    float* __restrict__ C,
    const float* __restrict__ bias) {
  constexpr int K = 768, LDC = 768, NTIL = K / 32;    // 24 K-tiles
  __shared__ u16 lds[2][(128 + 64) * 32];             // 24 KB
  const int tid = threadIdx.x;
  const int w = tid >> 6, l = tid & 63;
  const int lane16 = l & 15, quad = l >> 4;
  const int mh = (w & 1) * 64;
  const int nh = (w >> 1) * 32;

  const int orig = blockIdx.x;
  const int logical = (orig & 7) * 96 + (orig >> 3);  // bijective, 768/8=96
  const int i0 = (logical / 12) * 128, j0 = (logical % 12) * 64;

  f32x4 acc[4][2];
  #pragma unroll
  for (int m = 0; m < 4; m++)
    #pragma unroll
    for (int n = 0; n < 2; n++) acc[m][n] = (f32x4){0.f, 0.f, 0.f, 0.f};

  auto stage = [&](int buf, int t) {
    const int k0 = t * 32;
    u16* Ad = &lds[buf][0];
    #pragma unroll
    for (int s = 0; s < 2; s++) {
      int lin = tid + s * 256;
      int row = lin >> 2, j = lin & 3;
      gld16(&A[(size_t)(i0 + row) * K + k0 + ((j ^ ((row >> 1) & 3)) * 8)], &Ad[lin * 8]);
    }
    {
      u16* Bd = &lds[buf][128 * 32];
      int row = tid >> 2, j = tid & 3;
      gld16(&B[(size_t)(j0 + row) * K + k0 + ((j ^ ((row >> 1) & 3)) * 8)], &Bd[tid * 8]);
    }
  };

  stage(0, 0);
  stage(1, 1);                                        // 6 loads in flight
  asm volatile("s_waitcnt vmcnt(3)" ::: "memory");    // tile 0 landed
  __builtin_amdgcn_s_barrier();

  for (int t = 0; t < NTIL; t++) {
    const u16* Al = &lds[t & 1][0];
    const u16* Bl = &lds[t & 1][128 * 32];
    short8 bf[2], af[4];
    #pragma unroll
    for (int n = 0; n < 2; n++) {
      int row = nh + n * 16 + lane16;
      int ch = quad ^ ((row >> 1) & 3);
      bf[n] = *(const short8*)&Bl[row * 32 + ch * 8];
    }
    #pragma unroll
    for (int mi = 0; mi < 4; mi++) {
      int row = mh + mi * 16 + lane16;
      int ch = quad ^ ((row >> 1) & 3);
      af[mi] = *(const short8*)&Al[row * 32 + ch * 8];
    }
    asm volatile("s_waitcnt lgkmcnt(0)" ::: "memory");
    __builtin_amdgcn_sched_barrier(0);
    __builtin_amdgcn_s_barrier();
    if (t + 2 < NTIL) stage(t & 1, t + 2);
    __builtin_amdgcn_s_setprio(1);
    #pragma unroll
    for (int mi = 0; mi < 4; mi++)
      #pragma unroll
      for (int n = 0; n < 2; n++)
        acc[mi][n] = MFMA16(af[mi], bf[n], acc[mi][n]);
    __builtin_amdgcn_s_setprio(0);
    if (t + 2 < NTIL) asm volatile("s_waitcnt vmcnt(3)" ::: "memory");
    else              asm volatile("s_waitcnt vmcnt(0)" ::: "memory");
    __builtin_amdgcn_s_barrier();
  }

  #pragma unroll
  for (int m = 0; m < 4; m++) {
    #pragma unroll
    for (int n = 0; n < 2; n++) {
      int col = j0 + nh + n * 16 + lane16;
      #pragma unroll
      for (int r = 0; r < 4; r++) {
        int row = i0 + mh + m * 16 + quad * 4 + r;
        C[(size_t)row * LDC + col] = acc[m][n][r] + bias[col];
      }
    }
  }
}

// ---------------- Attention: EXACT r12 state (verified passing, 46.0us).
// r2: T14 async-STAGE + setprio + f32x4 lsum. r3: mkb_all mask table.
// r8: K0-fold + v_cvt_pk_bf16_f32 P-pack. Dead ends (confirmed): ones-row
// MFMA denominator (r10 NaN), K/V dbuf single-barrier + 64-wide XOR tiles
// (r13: -1us, VALU addressing cost > barrier savings).
// Block = 4 waves, 128 q-rows, grid 768 (3 blocks/CU), LDS 40KB.
__global__ __launch_bounds__(256, 3) void attn_mfma(
    const u16* __restrict__ qkv,   // bf16 bits, [B*N][2304]; q +0, k +768, v +1536 (+h*64)
    const int* __restrict__ mask,
    u16* __restrict__ ctx) {
  __shared__ u16 Ks[64][72];      // [key][dim]
  __shared__ u16 Vt[64][72];      // [dim][key]
  __shared__ u16 Ps[4][32][72];   // per-wave P [qrow_local][key]
  __shared__ float mkb_all[1024]; // K0 (valid) or -1e38 (masked) per key

  const int tid = threadIdx.x;
  const int w = tid >> 6, l = tid & 63;
  const int lane16 = l & 15, quad = l >> 4;
  const int idx = blockIdx.x;
  const int bh = idx % 96;        // 96 % 8 == 0 -> same bh => same XCD
  const int rb = idx / 96;
  const int b = bh / 12, h = bh % 12;
  const int n0 = rb * 128;
  const int baseRow = b * 1024;

  // exp(s/8 - 16) == exp2(s*K1 + K0); fixed max >> max score (~8 sigma), overflow-free.
  const float K1 = 0.18033688011112043f;   // log2(e)/8
  const float K0 = -23.083120654223415f;   // -16*log2(e)

  // staging thread mapping
  const int key_s = tid >> 2, ds_s = (tid & 3) * 16;      // K: 1 key, 32 dims
  const int kA_s = (tid & 31) * 2, dg_s = tid >> 5;       // V: 2 keys, 8 dims

  // whole-sequence mask bias table (written once; first compute barrier covers it)
  {
    int4 mv = *(const int4*)&mask[baseRow + tid * 4];
    f32x4 mf;
    mf[0] = mv.x ? K0 : -1e38f;
    mf[1] = mv.y ? K0 : -1e38f;
    mf[2] = mv.z ? K0 : -1e38f;
    mf[3] = mv.w ? K0 : -1e38f;
    *(f32x4*)&mkb_all[tid * 4] = mf;
  }

  // Q fragments (used as MFMA B operand): n=lane16 (local qrow), k=quad*8+j
  short8 qfrag[2][2];
  #pragma unroll
  for (int qt = 0; qt < 2; qt++) {
    const u16* qp = qkv + (size_t)(baseRow + n0 + w*32 + qt*16 + lane16) * 2304 + h*64;
    #pragma unroll
    for (int ks = 0; ks < 2; ks++)
      qfrag[qt][ks] = *(const short8*)(qp + ks*32 + quad*8);
  }

  f32x4 oacc[2][4];     // [qt][nt(dim)]; C-layout row=quad*4+r=qrow, col=lane16=dim
  #pragma unroll
  for (int qt = 0; qt < 2; qt++)
    #pragma unroll
    for (int nt = 0; nt < 4; nt++) oacc[qt][nt] = (f32x4){0.f, 0.f, 0.f, 0.f};
  f32x4 lsum4[2] = {(f32x4){0.f,0.f,0.f,0.f}, (f32x4){0.f,0.f,0.f,0.f}};

  // ---- T14 prologue: issue chunk-0 K/V loads into registers
  uint4 kr0, kr1, vr0, vr1;
  {
    const u16* kp = qkv + (size_t)(baseRow + key_s) * 2304 + 768 + h*64 + ds_s;
    kr0 = *(const uint4*)kp;
    kr1 = *(const uint4*)(kp + 8);
    const u16* vp = qkv + (size_t)(baseRow + kA_s) * 2304 + 1536 + h*64 + dg_s*8;
    vr0 = *(const uint4*)vp;
    vr1 = *(const uint4*)(vp + 2304);
  }

  for (int c = 0; c < 16; c++) {
    if (c) __syncthreads();   // prior chunk's LDS reads complete before overwrite

    // ---- write staged registers (chunk c) into LDS
    *(uint4*)&Ks[key_s][ds_s]     = kr0;
    *(uint4*)&Ks[key_s][ds_s + 8] = kr1;
    {
      const u16* va = (const u16*)&vr0;
      const u16* vb = (const u16*)&vr1;
      #pragma unroll
      for (int j = 0; j < 8; j++)
        *(unsigned int*)&Vt[dg_s*8 + j][kA_s] =
            (unsigned int)va[j] | ((unsigned int)vb[j] << 16);
    }

    // ---- issue chunk c+1's global loads (registers only; latency hides
    //      under this chunk's MFMA + softmax)
    if (c + 1 < 16) {
      const u16* kp = qkv + (size_t)(baseRow + (c+1)*64 + key_s) * 2304 + 768 + h*64 + ds_s;
      kr0 = *(const uint4*)kp;
      kr1 = *(const uint4*)(kp + 8);
      const u16* vp = qkv + (size_t)(baseRow + (c+1)*64 + kA_s) * 2304 + 1536 + h*64 + dg_s*8;
      vr0 = *(const uint4*)vp;
      vr1 = *(const uint4*)(vp + 2304);
    }
    __syncthreads();          // chunk c visible to all waves

    // S^T = K * Q^T : A=K (m=key), B=Q (n=qrow). C-layout: row=key, col=qrow.
    f32x4 sacc[4][2];
    #pragma unroll
    for (int kt = 0; kt < 4; kt++)
      #pragma unroll
      for (int qt = 0; qt < 2; qt++) sacc[kt][qt] = (f32x4){0.f, 0.f, 0.f, 0.f};
    #pragma unroll
    for (int ks = 0; ks < 2; ks++) {
      short8 kf[4];
      #pragma unroll
      for (int kt = 0; kt < 4; kt++)
        kf[kt] = *(const short8*)&Ks[kt*16 + lane16][ks*32 + quad*8];
      __builtin_amdgcn_s_setprio(1);
      #pragma unroll
      for (int kt = 0; kt < 4; kt++)
        #pragma unroll
        for (int qt = 0; qt < 2; qt++)
          sacc[kt][qt] = MFMA16(kf[kt], qfrag[qt][ks], sacc[kt][qt]);
      __builtin_amdgcn_s_setprio(0);
    }

    // softmax: e = exp2(fma(s, K1, mkb)) — mask bias IS the exp2 offset.
    // P-pack via v_cvt_pk_bf16_f32 (converts+packs 2 floats/inst).
    #pragma unroll
    for (int kt = 0; kt < 4; kt++) {
      f32x4 mk4 = *(const f32x4*)&mkb_all[c*64 + kt*16 + quad*4];   // contiguous keys
      #pragma unroll
      for (int qt = 0; qt < 2; qt++) {
        float e0 = __builtin_amdgcn_exp2f(fmaf(sacc[kt][qt][0], K1, mk4[0]));
        float e1 = __builtin_amdgcn_exp2f(fmaf(sacc[kt][qt][1], K1, mk4[1]));
        float e2 = __builtin_amdgcn_exp2f(fmaf(sacc[kt][qt][2], K1, mk4[2]));
        float e3 = __builtin_amdgcn_exp2f(fmaf(sacc[kt][qt][3], K1, mk4[3]));
        lsum4[qt][0] += e0; lsum4[qt][1] += e1;
        lsum4[qt][2] += e2; lsum4[qt][3] += e3;
        uint2 pv;
        asm("v_cvt_pk_bf16_f32 %0, %1, %2" : "=v"(pv.x) : "v"(e0), "v"(e1));
        asm("v_cvt_pk_bf16_f32 %0, %1, %2" : "=v"(pv.y) : "v"(e2), "v"(e3));
        *(uint2*)&Ps[w][qt*16 + lane16][kt*16 + quad*4] = pv;
      }
    }

    // O += P * V : A=P (m=qrow, k=key) own-wave LDS; B=V^T (n=dim, k=key) from Vt.
    #pragma unroll
    for (int kc = 0; kc < 2; kc++) {
      short8 pf[2], vf[4];
      #pragma unroll
      for (int qt = 0; qt < 2; qt++)
        pf[qt] = *(const short8*)&Ps[w][qt*16 + lane16][kc*32 + quad*8];
      #pragma unroll
      for (int nt = 0; nt < 4; nt++)
        vf[nt] = *(const short8*)&Vt[nt*16 + lane16][kc*32 + quad*8];
      __builtin_amdgcn_s_setprio(1);
      #pragma unroll
      for (int qt = 0; qt < 2; qt++)
        #pragma unroll
        for (int nt = 0; nt < 4; nt++)
          oacc[qt][nt] = MFMA16(pf[qt], vf[nt], oacc[qt][nt]);
      __builtin_amdgcn_s_setprio(0);
    }
  }

  // lsum: reduce across quads, then redistribute to the C-layout row owner.
  float linv[2][4];
  #pragma unroll
  for (int qt = 0; qt < 2; qt++) {
    float s = lsum4[qt][0] + lsum4[qt][1] + lsum4[qt][2] + lsum4[qt][3];
    s += __shfl_xor(s, 16);
    s += __shfl_xor(s, 32);   // every lane: total for qrow = its lane16 (tile qt)
    #pragma unroll
    for (int r = 0; r < 4; r++)
      linv[qt][r] = 1.0f / __shfl(s, quad*4 + r);
  }
  // store; masked query rows get exactly their own V row (bit-exact copy)
  #pragma unroll
  for (int qt = 0; qt < 2; qt++) {
    #pragma unroll
    for (int r = 0; r < 4; r++) {
      int rl = w*32 + qt*16 + quad*4 + r;
      int rg = n0 + rl;
      int mq = (mkb_all[n0 + rl] != -1e38f);
      #pragma unroll
      for (int nt = 0; nt < 4; nt++) {
        u16 outv;
        if (mq) {
          outv = f2bf(oacc[qt][nt][r] * linv[qt][r]);
        } else {
          outv = qkv[(size_t)(baseRow + rg) * 2304 + 1536 + h*64 + nt*16 + lane16];
        }
        ctx[(size_t)(baseRow + rg) * 768 + h*64 + nt*16 + lane16] = outv;
      }
    }
  }
}

extern "C" void kernel_launch(void* const* d_in, const int* in_sizes, int n_in,
                              void* d_out, int out_size, void* d_ws, size_t ws_size,
                              hipStream_t stream) {
  const float* x     = (const float*)d_in[0];
  const int*   mask  = (const int*)d_in[1];
  const float* Wqkv  = (const float*)d_in[2];
  const float* Wproj = (const float*)d_in[3];
  const float* bproj = (const float*)d_in[4];
  float* out = (float*)d_out;

  const int NX = 8192 * 768;
  const int NQ = 2304 * 768;
  const int NP = 768 * 768;

  char* wsb = (char*)d_ws;
  u16* qkv    = (u16*)wsb;                                  // 37.75 MB
  u16* ctx    = (u16*)(wsb + (size_t)8192 * 2304 * 2);      // 12.58 MB
  u16* xb     = (u16*)(wsb + (size_t)8192 * 2304 * 2 + (size_t)8192 * 768 * 2);
  u16* wqkvb  = xb + NX;
  u16* wprojb = wqkvb + NQ;

  int cvt_blocks = ((NX + NQ + NP) / 4 + 255) / 256;
  cvt_bf16<<<dim3(cvt_blocks), 256, 0, stream>>>(x, xb, NX, Wqkv, wqkvb, NQ, Wproj, wprojb, NP);

  gemm_qkv_p32<<<dim3(576), 512, 0, stream>>>(xb, wqkvb, qkv);
  attn_mfma<<<dim3(768), 256, 0, stream>>>(qkv, mask, ctx);
  gemm_proj_p32<<<dim3(768), 256, 0, stream>>>(ctx, wprojb, out, bproj);
}

// Round 15
// 182.263 us; speedup vs baseline: 1.0281x; 1.0028x over previous
//
#include <hip/hip_runtime.h>
#include <hip/hip_bf16.h>
#include <stdint.h>

// B=8, N=1024, D=768, H=12, hd=64
// cvt(x,Wqkv,Wproj -> bf16 ws) -> pipelined MFMA gemm qkv -> MFMA flash attention -> pipelined MFMA gemm proj
// r15: attn softmax/PV interleaved per 32-key half (PV(kc0) MFMAs overlap
// softmax(kt2,3) VALU — pure source reorder, no new ops). qkv/proj frozen.

typedef unsigned short u16;
typedef unsigned int u32;
typedef __attribute__((ext_vector_type(8))) short short8;
typedef __attribute__((ext_vector_type(4))) float f32x4;

#define MFMA16(a, b, c) __builtin_amdgcn_mfma_f32_16x16x32_bf16((a), (b), (c), 0, 0, 0)

static __device__ __forceinline__ u16 f2bf(float f) {
    __hip_bfloat16 h = __float2bfloat16(f);
    return *(u16*)&h;
}
// async global->LDS, 16B per lane; LDS dest must be wave-uniform base + lane*16
static __device__ __forceinline__ void gld16(const u16* g, u16* l) {
  __builtin_amdgcn_global_load_lds(
      (const __attribute__((address_space(1))) void*)g,
      (__attribute__((address_space(3))) void*)l, 16, 0, 0);
}

// ---------------- fp32 -> bf16 conversion of the three input tensors
__global__ __launch_bounds__(256) void cvt_bf16(
    const float* __restrict__ s0, u16* __restrict__ d0, int n0,
    const float* __restrict__ s1, u16* __restrict__ d1, int n1,
    const float* __restrict__ s2, u16* __restrict__ d2, int n2) {
  int i = (blockIdx.x * 256 + threadIdx.x) * 4;
  const float* s; u16* d;
  if (i < n0) { s = s0 + i; d = d0 + i; }
  else if ((i -= n0) < n1) { s = s1 + i; d = d1 + i; }
  else if ((i -= n1) < n2) { s = s2 + i; d = d2 + i; }
  else return;
  float4 v = *(const float4*)s;
  ushort4 o;
  o.x = f2bf(v.x); o.y = f2bf(v.y); o.z = f2bf(v.z); o.w = f2bf(v.w);
  *(ushort4*)d = o;
}

// ---------------- QKV GEMM, pipelined, BK=32, flat phase (r12, verified).
// BM=256 BN=128, 512 thr, LDS 48KB -> 2 blocks/CU. Flat phase: all 10 b128
// frags up-front (forces fat VGPR schedule vs r11's 56-reg serialization),
// lgkm(0)+sched_barrier+barrier, restage(t+2), 16 MFMA setprio, vmcnt(3).
// Swizzle ch ^= (row>>1)&3 both-sides. T1 chunked XCD swizzle.
__global__ __launch_bounds__(512, 4) void gemm_qkv_p32(
    const u16* __restrict__ A,
    const u16* __restrict__ B,
    u16* __restrict__ C) {
  constexpr int K = 768, LDC = 2304, NTIL = K / 32;   // 24 K-tiles
  __shared__ u16 lds[2][(256 + 128) * 32];            // 48 KB
  const int tid = threadIdx.x;
  const int w = tid >> 6, l = tid & 63;
  const int lane16 = l & 15, quad = l >> 4;
  const int wr = w >> 2, wc = w & 3;

  const int orig = blockIdx.x;
  const int logical = (orig & 7) * 72 + (orig >> 3);  // bijective, 576/8=72
  const int i0 = (logical / 18) * 256, j0 = (logical % 18) * 128;

  f32x4 acc[8][2];
  #pragma unroll
  for (int m = 0; m < 8; m++)
    #pragma unroll
    for (int n = 0; n < 2; n++) acc[m][n] = (f32x4){0.f, 0.f, 0.f, 0.f};

  auto stage = [&](int buf, int t) {
    const int k0 = t * 32;
    u16* Ad = &lds[buf][0];
    #pragma unroll
    for (int s = 0; s < 2; s++) {
      int lin = tid + s * 512;
      int row = lin >> 2, j = lin & 3;
      gld16(&A[(size_t)(i0 + row) * K + k0 + ((j ^ ((row >> 1) & 3)) * 8)], &Ad[lin * 8]);
    }
    {
      u16* Bd = &lds[buf][256 * 32];
      int row = tid >> 2, j = tid & 3;
      gld16(&B[(size_t)(j0 + row) * K + k0 + ((j ^ ((row >> 1) & 3)) * 8)], &Bd[tid * 8]);
    }
  };

  stage(0, 0);
  stage(1, 1);                                        // 6 loads in flight
  asm volatile("s_waitcnt vmcnt(3)" ::: "memory");    // tile 0 landed
  __builtin_amdgcn_s_barrier();

  for (int t = 0; t < NTIL; t++) {
    const u16* Al = &lds[t & 1][0];
    const u16* Bl = &lds[t & 1][256 * 32];
    short8 bf[2], af[8];
    #pragma unroll
    for (int n = 0; n < 2; n++) {
      int row = wc * 32 + n * 16 + lane16;
      int ch = quad ^ ((row >> 1) & 3);
      bf[n] = *(const short8*)&Bl[row * 32 + ch * 8];
    }
    #pragma unroll
    for (int mi = 0; mi < 8; mi++) {
      int row = wr * 128 + mi * 16 + lane16;
      int ch = quad ^ ((row >> 1) & 3);
      af[mi] = *(const short8*)&Al[row * 32 + ch * 8];
    }
    asm volatile("s_waitcnt lgkmcnt(0)" ::: "memory");
    __builtin_amdgcn_sched_barrier(0);
    __builtin_amdgcn_s_barrier();
    if (t + 2 < NTIL) stage(t & 1, t + 2);
    __builtin_amdgcn_s_setprio(1);
    #pragma unroll
    for (int mi = 0; mi < 8; mi++)
      #pragma unroll
      for (int n = 0; n < 2; n++)
        acc[mi][n] = MFMA16(af[mi], bf[n], acc[mi][n]);
    __builtin_amdgcn_s_setprio(0);
    if (t + 2 < NTIL) asm volatile("s_waitcnt vmcnt(3)" ::: "memory");
    else              asm volatile("s_waitcnt vmcnt(0)" ::: "memory");
    __builtin_amdgcn_s_barrier();
  }

  #pragma unroll
  for (int m = 0; m < 8; m++) {
    #pragma unroll
    for (int n = 0; n < 2; n++) {
      int col = j0 + wc * 32 + n * 16 + lane16;
      #pragma unroll
      for (int r = 0; r < 4; r++) {
        int row = i0 + wr * 128 + m * 16 + quad * 4 + r;
        C[(size_t)row * LDC + col] = f2bf(acc[m][n][r]);
      }
    }
  }
}

// ---------------- proj GEMM, pipelined, BK=32, flat phase (r14, verified).
// BM=128 BN=64, 256 thr, LDS 24KB, grid 768 = 3 blocks/CU. Flat phase:
// all 6 b128 frags up-front, lgkm(0)+sched_barrier+barrier, restage(t+2),
// 8 MFMA setprio, vmcnt(3).
__global__ __launch_bounds__(256, 3) void gemm_proj_p32(
    const u16* __restrict__ A,
    const u16* __restrict__ B,
    float* __restrict__ C,
    const float* __restrict__ bias) {
  constexpr int K = 768, LDC = 768, NTIL = K / 32;    // 24 K-tiles
  __shared__ u16 lds[2][(128 + 64) * 32];             // 24 KB
  const int tid = threadIdx.x;
  const int w = tid >> 6, l = tid & 63;
  const int lane16 = l & 15, quad = l >> 4;
  const int mh = (w & 1) * 64;
  const int nh = (w >> 1) * 32;

  const int orig = blockIdx.x;
  const int logical = (orig & 7) * 96 + (orig >> 3);  // bijective, 768/8=96
  const int i0 = (logical / 12) * 128, j0 = (logical % 12) * 64;

  f32x4 acc[4][2];
  #pragma unroll
  for (int m = 0; m < 4; m++)
    #pragma unroll
    for (int n = 0; n < 2; n++) acc[m][n] = (f32x4){0.f, 0.f, 0.f, 0.f};

  auto stage = [&](int buf, int t) {
    const int k0 = t * 32;
    u16* Ad = &lds[buf][0];
    #pragma unroll
    for (int s = 0; s < 2; s++) {
      int lin = tid + s * 256;
      int row = lin >> 2, j = lin & 3;
      gld16(&A[(size_t)(i0 + row) * K + k0 + ((j ^ ((row >> 1) & 3)) * 8)], &Ad[lin * 8]);
    }
    {
      u16* Bd = &lds[buf][128 * 32];
      int row = tid >> 2, j = tid & 3;
      gld16(&B[(size_t)(j0 + row) * K + k0 + ((j ^ ((row >> 1) & 3)) * 8)], &Bd[tid * 8]);
    }
  };

  stage(0, 0);
  stage(1, 1);                                        // 6 loads in flight
  asm volatile("s_waitcnt vmcnt(3)" ::: "memory");    // tile 0 landed
  __builtin_amdgcn_s_barrier();

  for (int t = 0; t < NTIL; t++) {
    const u16* Al = &lds[t & 1][0];
    const u16* Bl = &lds[t & 1][128 * 32];
    short8 bf[2], af[4];
    #pragma unroll
    for (int n = 0; n < 2; n++) {
      int row = nh + n * 16 + lane16;
      int ch = quad ^ ((row >> 1) & 3);
      bf[n] = *(const short8*)&Bl[row * 32 + ch * 8];
    }
    #pragma unroll
    for (int mi = 0; mi < 4; mi++) {
      int row = mh + mi * 16 + lane16;
      int ch = quad ^ ((row >> 1) & 3);
      af[mi] = *(const short8*)&Al[row * 32 + ch * 8];
    }
    asm volatile("s_waitcnt lgkmcnt(0)" ::: "memory");
    __builtin_amdgcn_sched_barrier(0);
    __builtin_amdgcn_s_barrier();
    if (t + 2 < NTIL) stage(t & 1, t + 2);
    __builtin_amdgcn_s_setprio(1);
    #pragma unroll
    for (int mi = 0; mi < 4; mi++)
      #pragma unroll
      for (int n = 0; n < 2; n++)
        acc[mi][n] = MFMA16(af[mi], bf[n], acc[mi][n]);
    __builtin_amdgcn_s_setprio(0);
    if (t + 2 < NTIL) asm volatile("s_waitcnt vmcnt(3)" ::: "memory");
    else              asm volatile("s_waitcnt vmcnt(0)" ::: "memory");
    __builtin_amdgcn_s_barrier();
  }

  #pragma unroll
  for (int m = 0; m < 4; m++) {
    #pragma unroll
    for (int n = 0; n < 2; n++) {
      int col = j0 + nh + n * 16 + lane16;
      #pragma unroll
      for (int r = 0; r < 4; r++) {
        int row = i0 + mh + m * 16 + quad * 4 + r;
        C[(size_t)row * LDC + col] = acc[m][n][r] + bias[col];
      }
    }
  }
}

// ---------------- Attention: MFMA flash, transposed-S, fixed-max softmax.
// r2: T14 async-STAGE + setprio + f32x4 lsum. r3: mkb_all mask table.
// r8: K0-fold + v_cvt_pk_bf16_f32 P-pack.
// r15: softmax/PV interleaved per 32-key half — PV(kc) depends only on
// softmax(kt=2kc,2kc+1); running softmax(kt2,3) VALU under PV(kc0)'s MFMAs
// uses both pipes (pure reorder; Ps is per-wave so program order suffices,
// same ordering discipline the all-then-all version relied on).
// Dead ends (confirmed): ones-row MFMA denom (r10 NaN); K/V dbuf
// single-barrier + 64-wide XOR tiles (r13: VALU addressing > barrier savings).
// Block = 4 waves, 128 q-rows, grid 768 (3 blocks/CU), LDS 40KB.
__global__ __launch_bounds__(256, 3) void attn_mfma(
    const u16* __restrict__ qkv,   // bf16 bits, [B*N][2304]; q +0, k +768, v +1536 (+h*64)
    const int* __restrict__ mask,
    u16* __restrict__ ctx) {
  __shared__ u16 Ks[64][72];      // [key][dim]
  __shared__ u16 Vt[64][72];      // [dim][key]
  __shared__ u16 Ps[4][32][72];   // per-wave P [qrow_local][key]
  __shared__ float mkb_all[1024]; // K0 (valid) or -1e38 (masked) per key

  const int tid = threadIdx.x;
  const int w = tid >> 6, l = tid & 63;
  const int lane16 = l & 15, quad = l >> 4;
  const int idx = blockIdx.x;
  const int bh = idx % 96;        // 96 % 8 == 0 -> same bh => same XCD
  const int rb = idx / 96;
  const int b = bh / 12, h = bh % 12;
  const int n0 = rb * 128;
  const int baseRow = b * 1024;

  // exp(s/8 - 16) == exp2(s*K1 + K0); fixed max >> max score (~8 sigma), overflow-free.
  const float K1 = 0.18033688011112043f;   // log2(e)/8
  const float K0 = -23.083120654223415f;   // -16*log2(e)

  // staging thread mapping
  const int key_s = tid >> 2, ds_s = (tid & 3) * 16;      // K: 1 key, 32 dims
  const int kA_s = (tid & 31) * 2, dg_s = tid >> 5;       // V: 2 keys, 8 dims

  // whole-sequence mask bias table (written once; first compute barrier covers it)
  {
    int4 mv = *(const int4*)&mask[baseRow + tid * 4];
    f32x4 mf;
    mf[0] = mv.x ? K0 : -1e38f;
    mf[1] = mv.y ? K0 : -1e38f;
    mf[2] = mv.z ? K0 : -1e38f;
    mf[3] = mv.w ? K0 : -1e38f;
    *(f32x4*)&mkb_all[tid * 4] = mf;
  }

  // Q fragments (used as MFMA B operand): n=lane16 (local qrow), k=quad*8+j
  short8 qfrag[2][2];
  #pragma unroll
  for (int qt = 0; qt < 2; qt++) {
    const u16* qp = qkv + (size_t)(baseRow + n0 + w*32 + qt*16 + lane16) * 2304 + h*64;
    #pragma unroll
    for (int ks = 0; ks < 2; ks++)
      qfrag[qt][ks] = *(const short8*)(qp + ks*32 + quad*8);
  }

  f32x4 oacc[2][4];     // [qt][nt(dim)]; C-layout row=quad*4+r=qrow, col=lane16=dim
  #pragma unroll
  for (int qt = 0; qt < 2; qt++)
    #pragma unroll
    for (int nt = 0; nt < 4; nt++) oacc[qt][nt] = (f32x4){0.f, 0.f, 0.f, 0.f};
  f32x4 lsum4[2] = {(f32x4){0.f,0.f,0.f,0.f}, (f32x4){0.f,0.f,0.f,0.f}};

  // ---- T14 prologue: issue chunk-0 K/V loads into registers
  uint4 kr0, kr1, vr0, vr1;
  {
    const u16* kp = qkv + (size_t)(baseRow + key_s) * 2304 + 768 + h*64 + ds_s;
    kr0 = *(const uint4*)kp;
    kr1 = *(const uint4*)(kp + 8);
    const u16* vp = qkv + (size_t)(baseRow + kA_s) * 2304 + 1536 + h*64 + dg_s*8;
    vr0 = *(const uint4*)vp;
    vr1 = *(const uint4*)(vp + 2304);
  }

  for (int c = 0; c < 16; c++) {
    if (c) __syncthreads();   // prior chunk's LDS reads complete before overwrite

    // ---- write staged registers (chunk c) into LDS
    *(uint4*)&Ks[key_s][ds_s]     = kr0;
    *(uint4*)&Ks[key_s][ds_s + 8] = kr1;
    {
      const u16* va = (const u16*)&vr0;
      const u16* vb = (const u16*)&vr1;
      #pragma unroll
      for (int j = 0; j < 8; j++)
        *(unsigned int*)&Vt[dg_s*8 + j][kA_s] =
            (unsigned int)va[j] | ((unsigned int)vb[j] << 16);
    }

    // ---- issue chunk c+1's global loads (registers only; latency hides
    //      under this chunk's MFMA + softmax)
    if (c + 1 < 16) {
      const u16* kp = qkv + (size_t)(baseRow + (c+1)*64 + key_s) * 2304 + 768 + h*64 + ds_s;
      kr0 = *(const uint4*)kp;
      kr1 = *(const uint4*)(kp + 8);
      const u16* vp = qkv + (size_t)(baseRow + (c+1)*64 + kA_s) * 2304 + 1536 + h*64 + dg_s*8;
      vr0 = *(const uint4*)vp;
      vr1 = *(const uint4*)(vp + 2304);
    }
    __syncthreads();          // chunk c visible to all waves

    // S^T = K * Q^T : A=K (m=key), B=Q (n=qrow). C-layout: row=key, col=qrow.
    f32x4 sacc[4][2];
    #pragma unroll
    for (int kt = 0; kt < 4; kt++)
      #pragma unroll
      for (int qt = 0; qt < 2; qt++) sacc[kt][qt] = (f32x4){0.f, 0.f, 0.f, 0.f};
    #pragma unroll
    for (int ks = 0; ks < 2; ks++) {
      short8 kf[4];
      #pragma unroll
      for (int kt = 0; kt < 4; kt++)
        kf[kt] = *(const short8*)&Ks[kt*16 + lane16][ks*32 + quad*8];
      __builtin_amdgcn_s_setprio(1);
      #pragma unroll
      for (int kt = 0; kt < 4; kt++)
        #pragma unroll
        for (int qt = 0; qt < 2; qt++)
          sacc[kt][qt] = MFMA16(kf[kt], qfrag[qt][ks], sacc[kt][qt]);
      __builtin_amdgcn_s_setprio(0);
    }

    // Interleaved softmax + PV per 32-key half: PV(kc) needs only
    // kt = 2kc, 2kc+1. softmax(kt2,3) VALU overlaps PV(kc0) MFMAs.
    #pragma unroll
    for (int kc = 0; kc < 2; kc++) {
      // softmax for this half's keys
      #pragma unroll
      for (int kth = 0; kth < 2; kth++) {
        int kt = kc * 2 + kth;
        f32x4 mk4 = *(const f32x4*)&mkb_all[c*64 + kt*16 + quad*4];   // contiguous keys
        #pragma unroll
        for (int qt = 0; qt < 2; qt++) {
          float e0 = __builtin_amdgcn_exp2f(fmaf(sacc[kt][qt][0], K1, mk4[0]));
          float e1 = __builtin_amdgcn_exp2f(fmaf(sacc[kt][qt][1], K1, mk4[1]));
          float e2 = __builtin_amdgcn_exp2f(fmaf(sacc[kt][qt][2], K1, mk4[2]));
          float e3 = __builtin_amdgcn_exp2f(fmaf(sacc[kt][qt][3], K1, mk4[3]));
          lsum4[qt][0] += e0; lsum4[qt][1] += e1;
          lsum4[qt][2] += e2; lsum4[qt][3] += e3;
          uint2 pv;
          asm("v_cvt_pk_bf16_f32 %0, %1, %2" : "=v"(pv.x) : "v"(e0), "v"(e1));
          asm("v_cvt_pk_bf16_f32 %0, %1, %2" : "=v"(pv.y) : "v"(e2), "v"(e3));
          *(uint2*)&Ps[w][qt*16 + lane16][kt*16 + quad*4] = pv;
        }
      }
      // PV for this half: A=P (m=qrow, k=key) own-wave LDS; B=V^T from Vt.
      short8 pf[2], vf[4];
      #pragma unroll
      for (int qt = 0; qt < 2; qt++)
        pf[qt] = *(const short8*)&Ps[w][qt*16 + lane16][kc*32 + quad*8];
      #pragma unroll
      for (int nt = 0; nt < 4; nt++)
        vf[nt] = *(const short8*)&Vt[nt*16 + lane16][kc*32 + quad*8];
      __builtin_amdgcn_s_setprio(1);
      #pragma unroll
      for (int qt = 0; qt < 2; qt++)
        #pragma unroll
        for (int nt = 0; nt < 4; nt++)
          oacc[qt][nt] = MFMA16(pf[qt], vf[nt], oacc[qt][nt]);
      __builtin_amdgcn_s_setprio(0);
    }
  }

  // lsum: reduce across quads, then redistribute to the C-layout row owner.
  float linv[2][4];
  #pragma unroll
  for (int qt = 0; qt < 2; qt++) {
    float s = lsum4[qt][0] + lsum4[qt][1] + lsum4[qt][2] + lsum4[qt][3];
    s += __shfl_xor(s, 16);
    s += __shfl_xor(s, 32);   // every lane: total for qrow = its lane16 (tile qt)
    #pragma unroll
    for (int r = 0; r < 4; r++)
      linv[qt][r] = 1.0f / __shfl(s, quad*4 + r);
  }
  // store; masked query rows get exactly their own V row (bit-exact copy)
  #pragma unroll
  for (int qt = 0; qt < 2; qt++) {
    #pragma unroll
    for (int r = 0; r < 4; r++) {
      int rl = w*32 + qt*16 + quad*4 + r;
      int rg = n0 + rl;
      int mq = (mkb_all[n0 + rl] != -1e38f);
      #pragma unroll
      for (int nt = 0; nt < 4; nt++) {
        u16 outv;
        if (mq) {
          outv = f2bf(oacc[qt][nt][r] * linv[qt][r]);
        } else {
          outv = qkv[(size_t)(baseRow + rg) * 2304 + 1536 + h*64 + nt*16 + lane16];
        }
        ctx[(size_t)(baseRow + rg) * 768 + h*64 + nt*16 + lane16] = outv;
      }
    }
  }
}

extern "C" void kernel_launch(void* const* d_in, const int* in_sizes, int n_in,
                              void* d_out, int out_size, void* d_ws, size_t ws_size,
                              hipStream_t stream) {
  const float* x     = (const float*)d_in[0];
  const int*   mask  = (const int*)d_in[1];
  const float* Wqkv  = (const float*)d_in[2];
  const float* Wproj = (const float*)d_in[3];
  const float* bproj = (const float*)d_in[4];
  float* out = (float*)d_out;

  const int NX = 8192 * 768;
  const int NQ = 2304 * 768;
  const int NP = 768 * 768;

  char* wsb = (char*)d_ws;
  u16* qkv    = (u16*)wsb;                                  // 37.75 MB
  u16* ctx    = (u16*)(wsb + (size_t)8192 * 2304 * 2);      // 12.58 MB
  u16* xb     = (u16*)(wsb + (size_t)8192 * 2304 * 2 + (size_t)8192 * 768 * 2);
  u16* wqkvb  = xb + NX;
  u16* wprojb = wqkvb + NQ;

  int cvt_blocks = ((NX + NQ + NP) / 4 + 255) / 256;
  cvt_bf16<<<dim3(cvt_blocks), 256, 0, stream>>>(x, xb, NX, Wqkv, wqkvb, NQ, Wproj, wprojb, NP);

  gemm_qkv_p32<<<dim3(576), 512, 0, stream>>>(xb, wqkvb, qkv);
  attn_mfma<<<dim3(768), 256, 0, stream>>>(qkv, mask, ctx);
  gemm_proj_p32<<<dim3(768), 256, 0, stream>>>(ctx, wprojb, out, bproj);
}